// Round 7
// baseline (353.207 us; speedup 1.0000x reference)
//
#include <hip/hip_runtime.h>
#include <stdint.h>
#include <math.h>

#define BATCH 32
#define NANCH 33600
#define N0 25600   // 160x160, stride 8
#define N1 6400    // 80x80,  stride 16
#define N2 1600    // 40x40,  stride 32
#define TOPK 1000
#define NBIN 4096
#define CCAP 2816
#define SB 4096    // anchors per score block
#define DETS_SIZE (BATCH * TOPK * 5)

// numpy-exact float32 sigmoid: exp in double (correctly rounded to f32), then f32 divide.
// Needed ONLY where ranking depends on exact score bits.
__device__ __forceinline__ float sigmoid_np(float x) {
    float e = (float)::exp(-(double)x);
    return 1.0f / (1.0f + e);
}

// ---------------- Kernel 0: init rank table (-1) + global histogram (0) ----------------
__global__ void init_kernel(int* __restrict__ rank, unsigned* __restrict__ ghist) {
    int i = blockIdx.x * blockDim.x + threadIdx.x;
    if (i < BATCH * NANCH) rank[i] = -1;
    if (i < BATCH * NBIN) ghist[i] = 0u;
}

// ---------------- Kernel 1: score S = sigmoid(cls)*sigmoid(obj) + LDS histogram ---------
__global__ __launch_bounds__(1024) void score_kernel(
        const float* __restrict__ cls0, const float* __restrict__ cls1,
        const float* __restrict__ cls2,
        const float* __restrict__ obj0, const float* __restrict__ obj1,
        const float* __restrict__ obj2,
        float* __restrict__ S, unsigned* __restrict__ ghist) {
    __shared__ unsigned hist[NBIN];
    const int tid = threadIdx.x;
    const int b = blockIdx.y;
    const int base = blockIdx.x * SB;
    for (int i = tid; i < NBIN; i += 1024) hist[i] = 0u;
    __syncthreads();

    #pragma unroll
    for (int q = 0; q < SB / 1024; ++q) {
        int n = base + q * 1024 + tid;
        if (n < NANCH) {
            const float* cp; const float* op; int nl;
            if (n < N0)            { cp = cls0 + (size_t)b * N0; op = obj0 + (size_t)b * N0; nl = n; }
            else if (n < N0 + N1)  { cp = cls1 + (size_t)b * N1; op = obj1 + (size_t)b * N1; nl = n - N0; }
            else                   { cp = cls2 + (size_t)b * N2; op = obj2 + (size_t)b * N2; nl = n - N0 - N1; }
            float sc = sigmoid_np(cp[nl]) * sigmoid_np(op[nl]);
            S[(size_t)b * NANCH + n] = sc;
            atomicAdd(&hist[__float_as_uint(sc) >> 19], 1u);  // LDS atomic
        }
    }
    __syncthreads();
    for (int i = tid; i < NBIN; i += 1024) {
        unsigned c = hist[i];
        if (c) atomicAdd(&ghist[(size_t)b * NBIN + i], c);
    }
}

// ---------------- Kernel 2: exact top-1000 per batch -> rank[b][n] ------------------------
__global__ __launch_bounds__(1024) void select_kernel(const float* __restrict__ S_g,
                                                      const unsigned* __restrict__ ghist,
                                                      int* __restrict__ rank) {
    const int b = blockIdx.x;
    const float* S = S_g + (size_t)b * NANCH;
    __shared__ unsigned scan[1024];
    __shared__ unsigned long long wbuf[TOPK];
    __shared__ unsigned long long cbuf[CCAP];
    __shared__ unsigned sh_T, sh_above, sh_d, sh_k2, wcnt, ccnt;
    const int tid = threadIdx.x;

    if (tid == 0) { wcnt = 0u; ccnt = 0u; }
    unsigned s0 = ghist[(size_t)b * NBIN + 4 * tid + 0];
    unsigned s1 = ghist[(size_t)b * NBIN + 4 * tid + 1];
    unsigned s2 = ghist[(size_t)b * NBIN + 4 * tid + 2];
    unsigned s3 = ghist[(size_t)b * NBIN + 4 * tid + 3];
    unsigned tot = s0 + s1 + s2 + s3;
    scan[tid] = tot;
    __syncthreads();
    for (int off = 1; off < 1024; off <<= 1) {
        unsigned v = scan[tid] + ((tid + off < 1024) ? scan[tid + off] : 0u);
        __syncthreads();
        scan[tid] = v;
        __syncthreads();
    }
    unsigned excl = scan[tid] - tot;  // keys in bins > 4t+3
    {
        unsigned a3 = excl,      f3 = excl + s3;
        unsigned a2 = f3,        f2 = f3 + s2;
        unsigned a1 = f2,        f1 = f2 + s1;
        unsigned a0 = f1,        f0 = f1 + s0;
        if (a3 < TOPK && f3 >= TOPK) { sh_T = 4u * tid + 3u; sh_above = a3; }
        if (a2 < TOPK && f2 >= TOPK) { sh_T = 4u * tid + 2u; sh_above = a2; }
        if (a1 < TOPK && f1 >= TOPK) { sh_T = 4u * tid + 1u; sh_above = a1; }
        if (a0 < TOPK && f0 >= TOPK) { sh_T = 4u * tid + 0u; sh_above = a0; }
    }
    __syncthreads();
    const unsigned T = sh_T;
    const unsigned above = sh_above;     // strict winners (bins > T), < TOPK
    const unsigned need = TOPK - above;  // taken from boundary bin T

    const float4* S4 = (const float4*)S;
    const int M4 = NANCH / 4;
    for (int i = tid; i < M4; i += 1024) {
        float4 v = S4[i];
        float c[4] = {v.x, v.y, v.z, v.w};
        #pragma unroll
        for (int q = 0; q < 4; ++q) {
            unsigned u = __float_as_uint(c[q]);
            unsigned bin = u >> 19;
            if (bin >= T) {
                unsigned n = (unsigned)(4 * i + q);
                unsigned long long key = ((unsigned long long)u << 32)
                                       | (unsigned long long)(0xFFFFFFFFu - n);
                if (bin > T) {
                    unsigned p = atomicAdd(&wcnt, 1u);
                    wbuf[p] = key;
                } else {
                    unsigned p = atomicAdd(&ccnt, 1u);
                    if (p < CCAP) cbuf[p] = key;
                }
            }
        }
    }
    __syncthreads();

    if (ccnt <= CCAP) {
        const int W = (int)wcnt;   // == above
        if (tid < W) {
            unsigned long long my = wbuf[tid];
            int r = 0;
            for (int j = 0; j < W; ++j) r += (wbuf[j] > my) ? 1 : 0;
            unsigned n = 0xFFFFFFFFu - (unsigned)(my & 0xFFFFFFFFULL);
            rank[(size_t)b * NANCH + n] = r;
        }
        const int C = (int)ccnt;
        if (tid < C) {
            unsigned long long my = cbuf[tid];
            int r = 0;
            for (int j = 0; j < C; ++j) r += (cbuf[j] > my) ? 1 : 0;
            if (r < (int)need) {
                unsigned n = 0xFFFFFFFFu - (unsigned)(my & 0xFFFFFFFFULL);
                rank[(size_t)b * NANCH + n] = (int)above + r;
            }
        }
    } else {
        // ---- fallback (boundary-bin overflow; not expected): 8x8-bit radix select ----
        unsigned long long prefix = 0ULL;
        unsigned k = TOPK;
        for (int pass = 7; pass >= 0; --pass) {
            if (tid < 256) scan[tid] = 0u;
            __syncthreads();
            const int shift = pass * 8;
            const unsigned long long prefmask =
                (pass == 7) ? 0ULL : (0xFFFFFFFFFFFFFFFFULL << (shift + 8));
            for (int i = tid; i < NANCH; i += 1024) {
                unsigned u = __float_as_uint(S[i]);
                unsigned long long key = ((unsigned long long)u << 32)
                                       | (unsigned long long)(0xFFFFFFFFu - (unsigned)i);
                if ((key & prefmask) == prefix)
                    atomicAdd(&scan[(unsigned)((key >> shift) & 0xFFULL)], 1u);
            }
            __syncthreads();
            if (tid == 0) {
                unsigned cum = 0; int d = 0;
                for (int v = 255; v >= 0; --v) {
                    unsigned c = scan[v];
                    if (cum + c >= k) { d = v; break; }
                    cum += c;
                }
                sh_d = (unsigned)d;
                sh_k2 = k - cum;
            }
            __syncthreads();
            prefix |= ((unsigned long long)sh_d) << shift;
            k = sh_k2;
            __syncthreads();
        }
        if (tid == 0) wcnt = 0u;
        __syncthreads();
        for (int i = tid; i < NANCH; i += 1024) {
            unsigned u = __float_as_uint(S[i]);
            unsigned long long key = ((unsigned long long)u << 32)
                                   | (unsigned long long)(0xFFFFFFFFu - (unsigned)i);
            if (key >= prefix) {
                unsigned pos = atomicAdd(&wcnt, 1u);
                wbuf[pos] = key;
            }
        }
        __syncthreads();
        const int m = (int)wcnt;   // == TOPK
        if (tid < m) {
            unsigned long long my = wbuf[tid];
            int r = 0;
            for (int j = 0; j < m; ++j) r += (wbuf[j] > my) ? 1 : 0;
            unsigned n = 0xFFFFFFFFu - (unsigned)(my & 0xFFFFFFFFULL);
            rank[(size_t)b * NANCH + n] = r;
        }
    }
}

// ---------------- Kernel 3: per-plane sequential sweep (kpt x/y + vis) --------------------
// Rounds 4-6 lesson: any per-anchor sweep interleaving 55 plane streams moves its ~75 MB
// of L3 misses at only ~1.1 TB/s (random-granule HBM pattern). 51 of the 56 outputs per
// kept row depend on exactly ONE plane, so sweep one plane per blockIdx.y: consecutive
// blocks walk each plane front-to-back -> sequential HBM miss stream; threads carry only
// a float4 + int4 load -> low VGPR, high occupancy. rank (4.3 MB) is re-read per plane
// but stays L2-resident (read in lockstep with the plane walk).
__global__ __launch_bounds__(256) void plane_sweep(
        const int* __restrict__ rank, const float* __restrict__ kpt,
        const float* __restrict__ vis, float* __restrict__ out,
        int HW, int Wdim, float s, int loff) {
    const int p = blockIdx.y;   // 0..50: 0..33 = kpt plane, 34..50 = vis plane
    const int b = blockIdx.z;
    const int n0 = (blockIdx.x * 256 + threadIdx.x) * 4;
    if (n0 >= HW) return;

    const int4 rr = *(const int4*)&rank[(size_t)b * NANCH + loff + n0];
    const float* src = (p < 34) ? &kpt[((size_t)b * 34 + p) * HW + n0]
                                : &vis[((size_t)b * 17 + (p - 34)) * HW + n0];
    const float4 v = *(const float4*)src;

    int k, comp;
    if (p < 34) { k = p >> 1; comp = p & 1; } else { k = p - 34; comp = 2; }

    const float vals[4] = {v.x, v.y, v.z, v.w};
    const int   rs[4]   = {rr.x, rr.y, rr.z, rr.w};
    #pragma unroll
    for (int q = 0; q < 4; ++q) {
        int r = rs[q];
        if (r >= 0) {
            int nl = n0 + q;
            float o;
            if (comp == 2) {
                o = 1.0f / (1.0f + expf(-vals[q]));   // value-only: expf is fine
            } else {
                float pxy = (float)(comp ? (nl / Wdim) : (nl % Wdim)) * s;
                o = vals[q] * s + pxy;
            }
            out[(size_t)DETS_SIZE + ((size_t)b * TOPK + r) * 51 + 3 * k + comp] = o;
        }
    }
}

// ---------------- Kernel 4: dets sweep (bbox x4 + S per level) ----------------------------
__global__ __launch_bounds__(256) void dets_sweep(
        const int* __restrict__ rank, const float* __restrict__ S,
        const float* __restrict__ bbox, float* __restrict__ out,
        int HW, int Wdim, float s, int loff) {
    const int b = blockIdx.y;
    const int n0 = (blockIdx.x * 256 + threadIdx.x) * 4;
    if (n0 >= HW) return;

    const int4 rr = *(const int4*)&rank[(size_t)b * NANCH + loff + n0];
    const float4 sx = *(const float4*)&S[(size_t)b * NANCH + loff + n0];
    const float4 x4 = *(const float4*)&bbox[((size_t)b * 4 + 0) * HW + n0];
    const float4 y4 = *(const float4*)&bbox[((size_t)b * 4 + 1) * HW + n0];
    const float4 w4 = *(const float4*)&bbox[((size_t)b * 4 + 2) * HW + n0];
    const float4 h4 = *(const float4*)&bbox[((size_t)b * 4 + 3) * HW + n0];

    const int   rs[4] = {rr.x, rr.y, rr.z, rr.w};
    const float bx[4] = {x4.x, x4.y, x4.z, x4.w};
    const float by[4] = {y4.x, y4.y, y4.z, y4.w};
    const float bw[4] = {w4.x, w4.y, w4.z, w4.w};
    const float bh[4] = {h4.x, h4.y, h4.z, h4.w};
    const float sc[4] = {sx.x, sx.y, sx.z, sx.w};
    #pragma unroll
    for (int q = 0; q < 4; ++q) {
        int r = rs[q];
        if (r >= 0) {
            int nl = n0 + q;
            float px = (float)(nl % Wdim) * s;
            float py = (float)(nl / Wdim) * s;
            float cx = bx[q] * s + px;
            float cy = by[q] * s + py;
            float hw_ = expf(bw[q]) * s * 0.5f;
            float hh  = expf(bh[q]) * s * 0.5f;
            float* o = out + ((size_t)b * TOPK + r) * 5;
            o[0] = cx - hw_;
            o[1] = cy - hh;
            o[2] = cx + hw_;
            o[3] = cy + hh;
            o[4] = sc[q];
        }
    }
}

extern "C" void kernel_launch(void* const* d_in, const int* in_sizes, int n_in,
                              void* d_out, int out_size, void* d_ws, size_t ws_size,
                              hipStream_t stream) {
    const float* cls0  = (const float*)d_in[0];
    const float* cls1  = (const float*)d_in[1];
    const float* cls2  = (const float*)d_in[2];
    const float* bbox0 = (const float*)d_in[3];
    const float* bbox1 = (const float*)d_in[4];
    const float* bbox2 = (const float*)d_in[5];
    const float* obj0  = (const float*)d_in[6];
    const float* obj1  = (const float*)d_in[7];
    const float* obj2  = (const float*)d_in[8];
    const float* kpt0  = (const float*)d_in[9];
    const float* kpt1  = (const float*)d_in[10];
    const float* kpt2  = (const float*)d_in[11];
    const float* vis0  = (const float*)d_in[12];
    const float* vis1  = (const float*)d_in[13];
    const float* vis2  = (const float*)d_in[14];
    float* out = (float*)d_out;

    char* ws = (char*)d_ws;
    float*    S     = (float*)ws;   ws += (size_t)BATCH * NANCH * sizeof(float);
    int*      rank  = (int*)ws;     ws += (size_t)BATCH * NANCH * sizeof(int);
    unsigned* ghist = (unsigned*)ws;

    const int initN = BATCH * NANCH;
    init_kernel<<<(initN + 255) / 256, 256, 0, stream>>>(rank, ghist);

    dim3 gs((NANCH + SB - 1) / SB, BATCH);
    score_kernel<<<gs, 1024, 0, stream>>>(cls0, cls1, cls2, obj0, obj1, obj2, S, ghist);

    select_kernel<<<BATCH, 1024, 0, stream>>>(S, ghist, rank);

    // per-level plane sweeps: grid (chunks, 51 planes, batch)
    dim3 g0((N0 + 1023) / 1024, 51, BATCH);
    dim3 g1((N1 + 1023) / 1024, 51, BATCH);
    dim3 g2((N2 + 1023) / 1024, 51, BATCH);
    plane_sweep<<<g0, 256, 0, stream>>>(rank, kpt0, vis0, out, N0, 160, 8.f, 0);
    plane_sweep<<<g1, 256, 0, stream>>>(rank, kpt1, vis1, out, N1, 80, 16.f, N0);
    plane_sweep<<<g2, 256, 0, stream>>>(rank, kpt2, vis2, out, N2, 40, 32.f, N0 + N1);

    dim3 d0((N0 + 1023) / 1024, BATCH);
    dim3 d1((N1 + 1023) / 1024, BATCH);
    dim3 d2((N2 + 1023) / 1024, BATCH);
    dets_sweep<<<d0, 256, 0, stream>>>(rank, S, bbox0, out, N0, 160, 8.f, 0);
    dets_sweep<<<d1, 256, 0, stream>>>(rank, S, bbox1, out, N1, 80, 16.f, N0);
    dets_sweep<<<d2, 256, 0, stream>>>(rank, S, bbox2, out, N2, 40, 32.f, N0 + N1);
}